// Round 2
// baseline (339.199 us; speedup 1.0000x reference)
//
#include <hip/hip_runtime.h>
#include <hip/hip_bf16.h>

typedef __attribute__((ext_vector_type(8))) short bf16x8;
typedef __attribute__((ext_vector_type(4))) float f32x4;

constexpr int SMALL = 512;
constexpr int LARGE = 1024;
constexpr int NTOK  = 4 * 2048;   // 8192 tokens
constexpr int TPB   = 32;         // tokens per block
constexpr int LDA   = SMALL + 8;  // LDS A stride in shorts: 1040 B = 260 dwords (== 4 mod 32 banks)

static __device__ __forceinline__ unsigned short f2bf(float f) {
    __hip_bfloat16 h = __float2bfloat16(f);  // RNE
    return *reinterpret_cast<unsigned short*>(&h);
}

// Kernel 1: coeffs (512x512 f32, row-major j,k) -> bf16 same layout (the GEMM B^T operand).
__global__ __launch_bounds__(256) void k_cvt_coeffs(const float* __restrict__ coeffs,
                                                    unsigned short* __restrict__ b_bf16) {
    int i = blockIdx.x * 256 + threadIdx.x;    // 0 .. 512*128-1
    int e = i << 2;
    const float4 cvec = *reinterpret_cast<const float4*>(coeffs + e);
    ushort4 b;
    b.x = f2bf(cvec.x); b.y = f2bf(cvec.y); b.z = f2bf(cvec.z); b.w = f2bf(cvec.w);
    *reinterpret_cast<ushort4*>(b_bf16 + e) = b;
}

// Kernel 2 (fused): per block of 32 tokens:
//   Phase A: gather W[id] rows -> out[:, 0:512] = W+R (f32) and As (bf16, LDS)
//   Phase B: 8-wave MFMA GEMM  out[:, 512:1024] = As @ C^T + R[:, 512:1024]
__global__ __launch_bounds__(512) void k_fused(const int* __restrict__ ids,
                                               const float* __restrict__ weight,
                                               const float* __restrict__ residual,
                                               const unsigned short* __restrict__ B,
                                               float* __restrict__ out) {
    __shared__ unsigned short As[TPB * LDA];
    __shared__ int s_ids[TPB];

    const int tid  = threadIdx.x;
    const int tok0 = blockIdx.x * TPB;

    if (tid < TPB) s_ids[tid] = ids[tok0 + tid];
    __syncthreads();

    // ---- Phase A: gather + first-half add + bf16 LDS stage ----
    // 512 threads: token t = tid&31, 32-column chunk c0 = (tid>>5)*32.
    {
        const int t  = tid & 31;
        const int c0 = (tid >> 5) * 32;
        const int id = s_ids[t];
        const float* wrow = weight   + (size_t)id * SMALL + c0;
        const float* rrow = residual + (size_t)id * LARGE + c0;
        float*       orow = out + (size_t)(tok0 + t) * LARGE + c0;
        unsigned short* arow = As + t * LDA + c0;
#pragma unroll
        for (int j = 0; j < 8; ++j) {
            const float4 w = *reinterpret_cast<const float4*>(wrow + 4 * j);
            const float4 r = *reinterpret_cast<const float4*>(rrow + 4 * j);
            float4 o;
            o.x = w.x + r.x; o.y = w.y + r.y; o.z = w.z + r.z; o.w = w.w + r.w;
            *reinterpret_cast<float4*>(orow + 4 * j) = o;
            ushort4 a;
            a.x = f2bf(w.x); a.y = f2bf(w.y); a.z = f2bf(w.z); a.w = f2bf(w.w);
            *reinterpret_cast<ushort4*>(arow + 4 * j) = a;
        }
    }
    __syncthreads();

    // ---- Phase B: GEMM. Wave wv: rows r0..r0+15, cols c0b..c0b+127 ----
    const int wv   = tid >> 6;            // 0..7
    const int lane = tid & 63;
    const int r0   = (wv & 1) * 16;
    const int c0b  = (wv >> 1) * 128;
    const int lr   = lane & 15;
    const int lk   = (lane >> 4) * 8;

    f32x4 acc[8] = {};
    const unsigned short* a_addr = As + (r0 + lr) * LDA + lk;
    const unsigned short* pb     = B + (size_t)(c0b + lr) * SMALL + lk;

    for (int k0 = 0; k0 < 512; k0 += 32) {
        const bf16x8 a = *reinterpret_cast<const bf16x8*>(a_addr + k0);
#pragma unroll
        for (int n = 0; n < 8; ++n) {
            const bf16x8 b = *reinterpret_cast<const bf16x8*>(pb + (size_t)n * 16 * SMALL + k0);
            acc[n] = __builtin_amdgcn_mfma_f32_16x16x32_bf16(a, b, acc[n], 0, 0, 0);
        }
    }

    // ---- Epilogue: C/D layout col=lane&15, row=(lane>>4)*4+reg [m89] ----
    const int rloc = r0 + (lane >> 4) * 4;
#pragma unroll
    for (int r = 0; r < 4; ++r) {
        const int trow = rloc + r;                 // token row within block
        const int id2  = s_ids[trow];
        const float* res = residual + (size_t)id2 * LARGE + SMALL + c0b + lr;
        float*       op  = out + (size_t)(tok0 + trow) * LARGE + SMALL + c0b + lr;
#pragma unroll
        for (int n = 0; n < 8; ++n)
            op[n * 16] = acc[n][r] + res[n * 16];
    }
}

extern "C" void kernel_launch(void* const* d_in, const int* in_sizes, int n_in,
                              void* d_out, int out_size, void* d_ws, size_t ws_size,
                              hipStream_t stream) {
    const int*   ids      = (const int*)d_in[0];
    const float* weight   = (const float*)d_in[1];
    const float* coeffs   = (const float*)d_in[2];
    const float* residual = (const float*)d_in[3];
    float*       out      = (float*)d_out;

    unsigned short* b_bf16 = (unsigned short*)d_ws;   // 512*512*2 = 512 KB

    k_cvt_coeffs<<<(512 * 128) / 256, 256, 0, stream>>>(coeffs, b_bf16);
    k_fused<<<NTOK / TPB, 512, 0, stream>>>(ids, weight, residual, b_bf16, out);
}

// Round 3
// 328.522 us; speedup vs baseline: 1.0325x; 1.0325x over previous
//
#include <hip/hip_runtime.h>
#include <hip/hip_bf16.h>

typedef __attribute__((ext_vector_type(8))) short bf16x8;
typedef __attribute__((ext_vector_type(4))) float f32x4;

constexpr int SMALL = 512;
constexpr int LARGE = 1024;
constexpr int NTOK  = 4 * 2048;   // 8192 tokens
constexpr int TPB   = 16;         // tokens per block
constexpr int LDA   = SMALL + 8;  // As stride in shorts: 1040 B = 260 dw == 4 mod 32 banks
constexpr int LDR   = SMALL + 4;  // Rs stride in floats: 516 dw == 4 mod 32 banks

static __device__ __forceinline__ unsigned short f2bf(float f) {
    __hip_bfloat16 h = __float2bfloat16(f);  // RNE
    return *reinterpret_cast<unsigned short*>(&h);
}

// Kernel 1: coeffs (512x512 f32, row-major j,k) -> bf16 same layout (GEMM B^T operand).
__global__ __launch_bounds__(256) void k_cvt_coeffs(const float* __restrict__ coeffs,
                                                    unsigned short* __restrict__ b_bf16) {
    int i = blockIdx.x * 256 + threadIdx.x;    // 0 .. 512*128-1
    int e = i << 2;
    const float4 cvec = *reinterpret_cast<const float4*>(coeffs + e);
    ushort4 b;
    b.x = f2bf(cvec.x); b.y = f2bf(cvec.y); b.z = f2bf(cvec.z); b.w = f2bf(cvec.w);
    *reinterpret_cast<ushort4*>(b_bf16 + e) = b;
}

// Kernel 2 (fused): per block of 16 tokens, 256 threads (4 waves):
//   Phase A: gather W[id], R[id] (full row, coalesced).
//            out[:,0:512] = W+R ; As = bf16(W) ; Rs = R[:,512:1024]
//   Phase B: 4-wave MFMA GEMM, wave w covers all 16 rows x cols [w*128, w*128+128)
//            out[:,512+c] = sum_k As*k B + Rs
__global__ __launch_bounds__(256) void k_fused(const int* __restrict__ ids,
                                               const float* __restrict__ weight,
                                               const float* __restrict__ residual,
                                               const unsigned short* __restrict__ B,
                                               float* __restrict__ out) {
    __shared__ unsigned short As[TPB * LDA];   // 16.6 KB
    __shared__ float          Rs[TPB * LDR];   // 33.0 KB
    __shared__ int s_ids[TPB];

    const int tid  = threadIdx.x;
    const int tok0 = blockIdx.x * TPB;

    if (tid < TPB) s_ids[tid] = ids[tok0 + tid];
    __syncthreads();

    // ---- Phase A: 16 threads per token, lane-contiguous float4 ----
    {
        const int t   = tid >> 4;        // token 0..15
        const int sub = tid & 15;        // 16 lanes cover 64 consecutive floats / iter
        const int id  = s_ids[t];
        const float* wrow = weight   + (size_t)id * SMALL;
        const float* rrow = residual + (size_t)id * LARGE;
        float*       orow = out + (size_t)(tok0 + t) * LARGE;
        unsigned short* arow = As + t * LDA;
        float*          rsrw = Rs + t * LDR;
#pragma unroll
        for (int j = 0; j < 8; ++j) {
            const int c = j * 64 + sub * 4;
            const float4 w = *reinterpret_cast<const float4*>(wrow + c);
            const float4 r = *reinterpret_cast<const float4*>(rrow + c);
            float4 o;
            o.x = w.x + r.x; o.y = w.y + r.y; o.z = w.z + r.z; o.w = w.w + r.w;
            *reinterpret_cast<float4*>(orow + c) = o;
            ushort4 a;
            a.x = f2bf(w.x); a.y = f2bf(w.y); a.z = f2bf(w.z); a.w = f2bf(w.w);
            *reinterpret_cast<ushort4*>(arow + c) = a;
        }
#pragma unroll
        for (int j = 0; j < 8; ++j) {
            const int c = j * 64 + sub * 4;                       // col within second half
            const float4 r = *reinterpret_cast<const float4*>(rrow + SMALL + c);
            *reinterpret_cast<float4*>(rsrw + c) = r;
        }
    }
    __syncthreads();

    // ---- Phase B: GEMM. Wave wv: rows 0..15, cols wv*128 .. +127 ----
    const int wv   = tid >> 6;            // 0..3
    const int lane = tid & 63;
    const int c0b  = wv * 128;
    const int lr   = lane & 15;
    const int lk   = (lane >> 4) * 8;

    f32x4 acc[8] = {};
    const unsigned short* a_addr = As + lr * LDA + lk;
    const unsigned short* pb     = B + (size_t)(c0b + lr) * SMALL + lk;

    for (int k0 = 0; k0 < 512; k0 += 32) {
        const bf16x8 a = *reinterpret_cast<const bf16x8*>(a_addr + k0);
#pragma unroll
        for (int n = 0; n < 8; ++n) {
            const bf16x8 b = *reinterpret_cast<const bf16x8*>(pb + (size_t)n * 16 * SMALL + k0);
            acc[n] = __builtin_amdgcn_mfma_f32_16x16x32_bf16(a, b, acc[n], 0, 0, 0);
        }
    }

    // ---- Epilogue: C/D layout col=lane&15, row=(lane>>4)*4+reg [m89]; R from LDS ----
    const int rloc = (lane >> 4) * 4;
#pragma unroll
    for (int r = 0; r < 4; ++r) {
        const int trow = rloc + r;                 // token row within block
        float*       op  = out + (size_t)(tok0 + trow) * LARGE + SMALL + c0b + lr;
        const float* rs  = Rs + trow * LDR + c0b + lr;
#pragma unroll
        for (int n = 0; n < 8; ++n)
            op[n * 16] = acc[n][r] + rs[n * 16];
    }
}

extern "C" void kernel_launch(void* const* d_in, const int* in_sizes, int n_in,
                              void* d_out, int out_size, void* d_ws, size_t ws_size,
                              hipStream_t stream) {
    const int*   ids      = (const int*)d_in[0];
    const float* weight   = (const float*)d_in[1];
    const float* coeffs   = (const float*)d_in[2];
    const float* residual = (const float*)d_in[3];
    float*       out      = (float*)d_out;

    unsigned short* b_bf16 = (unsigned short*)d_ws;   // 512*512*2 = 512 KB

    k_cvt_coeffs<<<(512 * 128) / 256, 256, 0, stream>>>(coeffs, b_bf16);
    k_fused<<<NTOK / TPB, 256, 0, stream>>>(ids, weight, residual, b_bf16, out);
}